// Round 8
// baseline (863.169 us; speedup 1.0000x reference)
//
#include <hip/hip_runtime.h>

// GCN 3-layer: N=100000, E=3200000, 128 -> 256 -> 256 -> 40
// Round 8: COLUMN-wise int8 quantization -> scales factor out of the neighbor
// loop; gather inner loop is packed-byte integer adds (accL += u & 0x00FF00FF
// etc., 5 VALU/neighbor, no per-neighbor scale). Signed tables use excess-128.
// W1/W2 single-bf16 (halves GEMM MFMA); W3 stays hi/lo. k_bin caches edges in
// LDS (one read of the 51 MB edge list).

#define NN   100000
#define NE   3200000
#define FIN  128
#define FH   256
#define FOUT 40
#define EPSV 1e-5f

#define BSH   7
#define NBKT  ((NN + 127) >> BSH)  // 782
#define CAPB  8192
#define CHNK  4096

typedef __attribute__((ext_vector_type(8))) short bf8;
typedef __attribute__((ext_vector_type(4))) float f32x4;

__device__ __forceinline__ unsigned short f2bf(float x) {
    unsigned int u = __float_as_uint(x);
    unsigned int r = u + 0x7fffu + ((u >> 16) & 1u);
    return (unsigned short)(r >> 16);
}
__device__ __forceinline__ float bf2f(unsigned short h) {
    return __uint_as_float(((unsigned int)h) << 16);
}
__device__ __forceinline__ void f2bf2(float x, unsigned short& hi, unsigned short& lo) {
    unsigned short h = f2bf(x);
    hi = h;
    lo = f2bf(x - bf2f(h));
}
__device__ __forceinline__ void amaxf(float* p, float v) {
    atomicMax((unsigned int*)p, __float_as_uint(v));   // v >= 0
}

// ---- pass 1: bin edges by dst>>7; edge pairs cached in LDS (single read) ----
__global__ __launch_bounds__(256) void k_bin(const int* __restrict__ ei,
                                             int* __restrict__ gcur,
                                             unsigned int* __restrict__ staging) {
    __shared__ int hcnt[NBKT];
    __shared__ int hbase[NBKT];
    __shared__ int2 epair[CHNK];   // 32 KB
    __shared__ int sflag;
    const int tid = threadIdx.x;
    const int e0 = blockIdx.x * CHNK;
    for (int b = tid; b < NBKT; b += 256) hcnt[b] = 0;
    if (tid == 0) {
        int zz = 0;
        for (int i = 0; i < 64; i++) zz |= ei[2 * i + 1];
        sflag = (zz == 0) ? 1 : 0;
    }
    __syncthreads();
    const int f = sflag;
    for (int r = 0; r < CHNK / 256; r++) {
        int e = e0 + r * 256 + tid;
        if (e < NE) {
            int s, d;
            if (f) {
                s = ((const int2*)ei)[e].x;
                d = ((const int2*)ei)[NE + e].x;
            } else {
                s = ei[e];
                d = ei[NE + e];
            }
            epair[r * 256 + tid] = make_int2(s, d);
            atomicAdd(&hcnt[d >> BSH], 1);
        }
    }
    __syncthreads();
    for (int b = tid; b < NBKT; b += 256) {
        int c = hcnt[b];
        hbase[b] = c ? atomicAdd(&gcur[b], c) : 0;
    }
    __syncthreads();
    for (int b = tid; b < NBKT; b += 256) hcnt[b] = 0;
    __syncthreads();
    for (int r = 0; r < CHNK / 256; r++) {
        int e = e0 + r * 256 + tid;
        if (e < NE) {
            int2 p = epair[r * 256 + tid];
            int b = p.y >> BSH;
            int loc = atomicAdd(&hcnt[b], 1);
            int pos = hbase[b] + loc;
            if (pos < CAPB)
                staging[(size_t)b * CAPB + pos] =
                    (unsigned int)p.x | ((unsigned int)(p.y & 127) << 17);
        }
    }
}

__global__ void k_bucketscan(const int* __restrict__ gcur, int* __restrict__ bbase) {
    __shared__ int sb2[2][256];
    int t = threadIdx.x;
    int base = t * 4;
    int v0 = (base + 0 < NBKT) ? gcur[base + 0] : 0;
    int v1 = (base + 1 < NBKT) ? gcur[base + 1] : 0;
    int v2 = (base + 2 < NBKT) ? gcur[base + 2] : 0;
    int v3 = (base + 3 < NBKT) ? gcur[base + 3] : 0;
    int s0 = v0, s1 = s0 + v1, s2 = s1 + v2, s3 = s2 + v3;
    sb2[0][t] = s3;
    __syncthreads();
    int pi = 0;
    for (int off = 1; off < 256; off <<= 1) {
        int x = sb2[pi][t];
        if (t >= off) x += sb2[pi][t - off];
        sb2[pi ^ 1][t] = x;
        __syncthreads();
        pi ^= 1;
    }
    int excl = sb2[pi][t] - s3;
    if (base + 0 < NBKT) bbase[base + 0] = excl;
    if (base + 1 < NBKT) bbase[base + 1] = excl + s0;
    if (base + 2 < NBKT) bbase[base + 2] = excl + s1;
    if (base + 3 < NBKT) bbase[base + 3] = excl + s2;
}

// ---- pass 2: per-bucket build of cnt/dinv/rowptr/csr ----
__global__ __launch_bounds__(256) void k_build(const unsigned int* __restrict__ staging,
                                               const int* __restrict__ gcur,
                                               const int* __restrict__ bbase,
                                               int* __restrict__ cntg,
                                               float* __restrict__ dinv,
                                               int* __restrict__ rowptr,
                                               int* __restrict__ csr) {
    __shared__ int lcnt[128];
    __shared__ int lscan[2][128];
    __shared__ int lcur[128];
    const int tid = threadIdx.x;
    const int b = blockIdx.x;
    const int tot = min(gcur[b], CAPB);
    const int bb = bbase[b];
    const unsigned int* st = staging + (size_t)b * CAPB;
    if (tid < 128) lcnt[tid] = 0;
    __syncthreads();
    for (int i = tid; i < tot; i += 256) {
        unsigned int v = st[i];
        atomicAdd(&lcnt[v >> 17], 1);
    }
    __syncthreads();
    int pi = 0;
    if (tid < 128) lscan[0][tid] = lcnt[tid];
    __syncthreads();
    for (int off = 1; off < 128; off <<= 1) {
        if (tid < 128) {
            int x = lscan[pi][tid];
            if (tid >= off) x += lscan[pi][tid - off];
            lscan[pi ^ 1][tid] = x;
        }
        __syncthreads();
        pi ^= 1;
    }
    if (tid < 128) {
        int c = lcnt[tid];
        int excl = lscan[pi][tid] - c;
        lcur[tid] = excl;
        int node = (b << BSH) + tid;
        if (node < NN) {
            cntg[node] = c;
            dinv[node] = rsqrtf((float)(c + 1));
            rowptr[node] = bb + excl;
        }
    }
    __syncthreads();
    for (int i = tid; i < tot; i += 256) {
        unsigned int v = st[i];
        int pos = atomicAdd(&lcur[v >> 17], 1);
        csr[bb + pos] = (int)(v & 0x1ffffu);
    }
}

// ---- fused weight prep: W1/W2 hi only, W3 hi+lo; fragment-contiguous ----
__global__ void k_wprep(const float* __restrict__ W1, unsigned short* __restrict__ W1h,
                        const float* __restrict__ W2, unsigned short* __restrict__ W2h,
                        const float* __restrict__ W3, unsigned short* __restrict__ W3h,
                        unsigned short* __restrict__ W3l) {
    int idx = blockIdx.x * blockDim.x + threadIdx.x;
    const float* W;
    unsigned short *Wh, *Wl = nullptr;
    int K, M, MP;
    if (idx < 256 * 128) {
        W = W1; Wh = W1h; K = 128; M = 256; MP = 256;
    } else if (idx < 256 * 128 + 256 * 256) {
        idx -= 256 * 128;
        W = W2; Wh = W2h; K = 256; M = 256; MP = 256;
    } else if (idx < 256 * 128 + 256 * 256 + 64 * 256) {
        idx -= 256 * 128 + 256 * 256;
        W = W3; Wh = W3h; Wl = W3l; K = 256; M = 40; MP = 64;
    } else {
        return;
    }
    int m = idx / K, k = idx - m * K;
    float v = (m < M) ? W[(size_t)k * M + m] : 0.f;
    size_t dst = ((size_t)(k >> 5) * MP + m) * 32 + (k & 31);
    if (Wl) {
        unsigned short h, l;
        f2bf2(v, h, l);
        Wh[dst] = h;
        Wl[dst] = l;
    } else {
        Wh[dst] = f2bf(v);
    }
}

// ---- column max of |z*dinv| (128 cols) ----
__global__ __launch_bounds__(256) void k_cmaxZ(const float* __restrict__ z,
                                               const float* __restrict__ dinv,
                                               float* __restrict__ cmZ) {
    const int t = threadIdx.x;
    const int tr = t >> 6;          // 0..3
    const int c2 = (t & 63) * 2;
    const int rb = blockIdx.x * 256;
    float m0 = 0.f, m1 = 0.f;
    for (int i = 0; i < 64; i++) {
        int row = rb + tr + 4 * i;
        if (row < NN) {
            float2 v = *(const float2*)(z + (size_t)row * FIN + c2);
            float d = dinv[row];
            m0 = fmaxf(m0, fabsf(v.x * d));
            m1 = fmaxf(m1, fabsf(v.y * d));
        }
    }
    amaxf(&cmZ[c2], m0);
    amaxf(&cmZ[c2 + 1], m1);
}

// ---- z*dinv -> excess-128 int8 with column scales ----
__global__ __launch_bounds__(256) void k_zpb8(const float* __restrict__ z,
                                              const float* __restrict__ dinv,
                                              const float* __restrict__ cmZ,
                                              unsigned char* __restrict__ zp8) {
    int i = blockIdx.x * blockDim.x + threadIdx.x;
    if (i >= NN * 64) return;
    int row = i >> 6;
    int c = (i & 63) * 2;
    float2 v = *(const float2*)(z + (size_t)row * FIN + c);
    float d = dinv[row];
    float m0 = cmZ[c], m1 = cmZ[c + 1];
    float i0 = m0 > 0.f ? 127.f / m0 : 0.f;
    float i1 = m1 > 0.f ? 127.f / m1 : 0.f;
    int q0 = (int)rintf(v.x * d * i0) + 128;
    int q1 = (int)rintf(v.y * d * i1) + 128;
    *(unsigned short*)(zp8 + (size_t)row * FIN + c) =
        (unsigned short)((q0 & 0xff) | ((q1 & 0xff) << 8));
}

// ---- column max of relu(bn(x1))*dinv (256 cols) ----
__global__ __launch_bounds__(256) void k_cmaxY(const unsigned short* __restrict__ x1,
                                               const float* __restrict__ scale,
                                               const float* __restrict__ shift,
                                               const float* __restrict__ dinv,
                                               float* __restrict__ cmY) {
    const int t = threadIdx.x;
    const int tr = t >> 7;          // 0..1
    const int c2 = (t & 127) * 2;
    const int rb = blockIdx.x * 256;
    const float s0 = scale[c2], s1 = scale[c2 + 1];
    const float h0 = shift[c2], h1 = shift[c2 + 1];
    float m0 = 0.f, m1 = 0.f;
    for (int i = 0; i < 128; i++) {
        int row = rb + tr + 2 * i;
        if (row < NN) {
            unsigned int u = *(const unsigned int*)(x1 + (size_t)row * 256 + c2);
            float d = dinv[row];
            float v0 = fmaxf(__uint_as_float(u << 16) * s0 + h0, 0.f) * d;
            float v1 = fmaxf(__uint_as_float(u & 0xffff0000u) * s1 + h1, 0.f) * d;
            m0 = fmaxf(m0, v0);
            m1 = fmaxf(m1, v1);
        }
    }
    amaxf(&cmY[c2], m0);
    amaxf(&cmY[c2 + 1], m1);
}

// ---- BN+ReLU+dinv -> unsigned int8 with column scales ----
__global__ __launch_bounds__(256) void k_bnr8(const unsigned short* __restrict__ x,
                                              const float* __restrict__ scale,
                                              const float* __restrict__ shift,
                                              const float* __restrict__ dinv,
                                              const float* __restrict__ cmY,
                                              unsigned char* __restrict__ y8) {
    int i = blockIdx.x * blockDim.x + threadIdx.x;
    if (i >= NN * 64) return;
    int row = i >> 6;
    int c = (i & 63) * 4;
    uint2 u = *(const uint2*)(x + (size_t)row * 256 + c);
    float4 sc = *(const float4*)(scale + c);
    float4 sh = *(const float4*)(shift + c);
    float4 cm = *(const float4*)(cmY + c);
    float d = dinv[row];
    float v0 = fmaxf(__uint_as_float(u.x << 16) * sc.x + sh.x, 0.f) * d;
    float v1 = fmaxf(__uint_as_float(u.x & 0xffff0000u) * sc.y + sh.y, 0.f) * d;
    float v2 = fmaxf(__uint_as_float(u.y << 16) * sc.z + sh.z, 0.f) * d;
    float v3 = fmaxf(__uint_as_float(u.y & 0xffff0000u) * sc.w + sh.w, 0.f) * d;
    float i0 = cm.x > 0.f ? 255.f / cm.x : 0.f;
    float i1 = cm.y > 0.f ? 255.f / cm.y : 0.f;
    float i2 = cm.z > 0.f ? 255.f / cm.z : 0.f;
    float i3 = cm.w > 0.f ? 255.f / cm.w : 0.f;
    unsigned int q0 = (unsigned int)(v0 * i0 + 0.5f);
    unsigned int q1 = (unsigned int)(v1 * i1 + 0.5f);
    unsigned int q2 = (unsigned int)(v2 * i2 + 0.5f);
    unsigned int q3 = (unsigned int)(v3 * i3 + 0.5f);
    *(unsigned int*)(y8 + (size_t)row * 256 + c) = q0 | (q1 << 8) | (q2 << 16) | (q3 << 24);
}

// ---- int8 gather with packed integer accumulation, column scales ----
// F=256: unsigned, uint payload (4 cols/lane); F=128: excess-128, ushort (2 cols).
template <int F, bool SIGNED>
__global__ __launch_bounds__(256) void k_agg8(const unsigned char* __restrict__ tab,
                                              const float* __restrict__ colmax,
                                              const float* __restrict__ dinv,
                                              const int* __restrict__ rowptr,
                                              const int* __restrict__ cnt,
                                              const int* __restrict__ csr,
                                              unsigned short* __restrict__ oa) {
    const int wid = threadIdx.x >> 6;
    const int lane = threadIdx.x & 63;
    const int wstep = (blockDim.x >> 6) * gridDim.x;
    constexpr int B = F / 64;
    constexpr unsigned int MSK = (B == 4) ? 0x00FF00FFu : 0x000000FFu;
    const int off = lane * B;
    float cs[B];
#pragma unroll
    for (int k = 0; k < B; k++)
        cs[k] = colmax[off + k] * (SIGNED ? (1.f / 127.f) : (1.f / 255.f));
    for (int row = blockIdx.x * (blockDim.x >> 6) + wid; row < NN; row += wstep) {
        float fa[B];
        // self term
        {
            unsigned int su;
            if constexpr (B == 4) su = *(const unsigned int*)(tab + (size_t)row * F + off);
            else su = *(const unsigned short*)(tab + (size_t)row * F + off);
            fa[0] = (float)(su & 0xffu);
            fa[1] = (float)((su >> 8) & 0xffu);
            if constexpr (B == 4) {
                fa[2] = (float)((su >> 16) & 0xffu);
                fa[3] = (float)(su >> 24);
            }
        }
        const int rp = rowptr[row];
        const int cn = cnt[row];
        for (int e = 0; e < cn; e += 64) {
            int rem = min(cn - e, 64);
            int myidx = (lane < rem) ? csr[rp + e + lane] : 0;
            unsigned int accL = 0, accH = 0;
            int q = 0;
            for (; q + 8 <= rem; q += 8) {
                unsigned int u[8];
#pragma unroll
                for (int j = 0; j < 8; j++) {
                    int idx = __shfl(myidx, q + j);
                    if constexpr (B == 4)
                        u[j] = *(const unsigned int*)(tab + (size_t)idx * F + off);
                    else
                        u[j] = *(const unsigned short*)(tab + (size_t)idx * F + off);
                }
#pragma unroll
                for (int j = 0; j < 8; j++) {
                    accL += u[j] & MSK;
                    accH += (u[j] >> 8) & MSK;
                }
            }
            for (; q < rem; q++) {
                int idx = __shfl(myidx, q);
                unsigned int u;
                if constexpr (B == 4)
                    u = *(const unsigned int*)(tab + (size_t)idx * F + off);
                else
                    u = *(const unsigned short*)(tab + (size_t)idx * F + off);
                accL += u & MSK;
                accH += (u >> 8) & MSK;
            }
            if constexpr (B == 4) {
                fa[0] += (float)(accL & 0xFFFFu);
                fa[2] += (float)(accL >> 16);
                fa[1] += (float)(accH & 0xFFFFu);
                fa[3] += (float)(accH >> 16);
            } else {
                fa[0] += (float)accL;
                fa[1] += (float)accH;
            }
        }
        float d = dinv[row];
        float va[B];
        if constexpr (SIGNED) {
            float nb = 128.f * (float)(cn + 1);
#pragma unroll
            for (int k = 0; k < B; k++) va[k] = cs[k] * (fa[k] - nb);
        } else {
#pragma unroll
            for (int k = 0; k < B; k++) va[k] = cs[k] * fa[k];
        }
        size_t p = (size_t)row * F + off;
        if constexpr (B == 4) {
            uint2 o;
            o.x = (unsigned int)f2bf(va[0] * d) | ((unsigned int)f2bf(va[1] * d) << 16);
            o.y = (unsigned int)f2bf(va[2] * d) | ((unsigned int)f2bf(va[3] * d) << 16);
            *(uint2*)(oa + p) = o;
        } else {
            *(unsigned int*)(oa + p) =
                (unsigned int)f2bf(va[0] * d) | ((unsigned int)f2bf(va[1] * d) << 16);
        }
    }
}

// ---- GEMM: 64-row x 128-col tile; A bf16, W single bf16; bias + BN stats ----
template <int K>
__global__ __launch_bounds__(256) void k_gemm(const unsigned short* __restrict__ A,
                                              const unsigned short* __restrict__ Wth,
                                              const float* __restrict__ bias,
                                              unsigned short* __restrict__ outX,
                                              float* __restrict__ s1,
                                              float* __restrict__ s2) {
    __shared__ unsigned short sA[64][40];
    const int t = threadIdx.x;
    const int w = t >> 6, lane = t & 63;
    const int quad = lane >> 4, l16 = lane & 15;
    const int rowBase = blockIdx.y * 64;
    const int colW = blockIdx.x * 128 + w * 32;
    f32x4 acc[4][2];
#pragma unroll
    for (int i = 0; i < 4; i++)
#pragma unroll
        for (int j = 0; j < 2; j++) acc[i][j] = (f32x4)0.f;

    for (int k0 = 0; k0 < K; k0 += 32) {
        int gr = rowBase + (t >> 2);
        int4 v = {0, 0, 0, 0};
        if (gr < NN) v = *(const int4*)(A + (size_t)gr * K + k0 + (t & 3) * 8);
        __syncthreads();
        *(int4*)&sA[t >> 2][(t & 3) * 8] = v;
        __syncthreads();
        const int kb = k0 >> 5;
        bf8 bh[2];
#pragma unroll
        for (int j = 0; j < 2; j++) {
            size_t bo = ((size_t)(kb * 256 + colW + j * 16 + l16)) * 32 + quad * 8;
            bh[j] = *(const bf8*)(Wth + bo);
        }
#pragma unroll
        for (int i = 0; i < 4; i++) {
            bf8 a = *(const bf8*)&sA[i * 16 + l16][quad * 8];
#pragma unroll
            for (int j = 0; j < 2; j++)
                acc[i][j] = __builtin_amdgcn_mfma_f32_16x16x32_bf16(a, bh[j], acc[i][j], 0, 0, 0);
        }
    }
#pragma unroll
    for (int j = 0; j < 2; j++) {
        int col = colW + j * 16 + l16;
        float b = bias[col];
        float s1p = 0.f, s2p = 0.f;
#pragma unroll
        for (int i = 0; i < 4; i++) {
#pragma unroll
            for (int r = 0; r < 4; r++) {
                int row = rowBase + i * 16 + quad * 4 + r;
                if (row < NN) {
                    float v = acc[i][j][r] + b;
                    s1p += v;
                    s2p += v * v;
                    outX[(size_t)row * 256 + col] = f2bf(v);
                }
            }
        }
        s1p += __shfl_xor(s1p, 16); s1p += __shfl_xor(s1p, 32);
        s2p += __shfl_xor(s2p, 16); s2p += __shfl_xor(s2p, 32);
        if (quad == 0) {
            atomicAdd(&s1[col], s1p);
            atomicAdd(&s2[col], s2p);
        }
    }
}

// ---- layer-3 GEMM -> bf16 H3 (40 cols) + column absmax ----
__global__ __launch_bounds__(256) void k_mgemm3(const unsigned short* __restrict__ y2,
                                                const unsigned short* __restrict__ Wth,
                                                const unsigned short* __restrict__ Wtl,
                                                unsigned short* __restrict__ H3,
                                                float* __restrict__ cmH) {
    __shared__ unsigned short sA[128][40];
    const int t = threadIdx.x;
    const int w = t >> 6, lane = t & 63;
    const int quad = lane >> 4, l16 = lane & 15;
    const int rowBase = blockIdx.x << 7;
    f32x4 acc[8];
#pragma unroll
    for (int i = 0; i < 8; i++) acc[i] = (f32x4)0.f;

    for (int k0 = 0; k0 < 256; k0 += 32) {
        const int kb = k0 >> 5;
        int id0 = t, id1 = t + 256;
        int gr0 = rowBase + (id0 >> 2), gr1 = rowBase + (id1 >> 2);
        int4 zz = {0, 0, 0, 0};
        int4 v0 = (gr0 < NN) ? *(const int4*)(y2 + (size_t)gr0 * 256 + k0 + (id0 & 3) * 8) : zz;
        int4 v1 = (gr1 < NN) ? *(const int4*)(y2 + (size_t)gr1 * 256 + k0 + (id1 & 3) * 8) : zz;
        __syncthreads();
        *(int4*)&sA[id0 >> 2][(id0 & 3) * 8] = v0;
        *(int4*)&sA[id1 >> 2][(id1 & 3) * 8] = v1;
        __syncthreads();
        size_t bo = ((size_t)(kb * 64 + w * 16 + l16)) * 32 + quad * 8;
        bf8 bh = *(const bf8*)(Wth + bo);
        bf8 bl = *(const bf8*)(Wtl + bo);
#pragma unroll
        for (int i = 0; i < 8; i++) {
            bf8 a = *(const bf8*)&sA[i * 16 + l16][quad * 8];
            acc[i] = __builtin_amdgcn_mfma_f32_16x16x32_bf16(a, bh, acc[i], 0, 0, 0);
            acc[i] = __builtin_amdgcn_mfma_f32_16x16x32_bf16(a, bl, acc[i], 0, 0, 0);
        }
    }
    const int col = w * 16 + l16;
    float tmax = 0.f;
#pragma unroll
    for (int i = 0; i < 8; i++) {
#pragma unroll
        for (int r = 0; r < 4; r++) {
            tmax = fmaxf(tmax, fabsf(acc[i][r]));
            int row = rowBase + i * 16 + quad * 4 + r;
            if (col < FOUT && row < NN) H3[(size_t)row * FOUT + col] = f2bf(acc[i][r]);
        }
    }
    tmax = fmaxf(tmax, __shfl_xor(tmax, 16));
    tmax = fmaxf(tmax, __shfl_xor(tmax, 32));
    if (quad == 0 && col < FOUT) amaxf(&cmH[col], tmax);
}

// ---- quantize H3 -> excess-128 int8, 64-col padded (pad = 128) ----
__global__ __launch_bounds__(256) void k_quantH(const unsigned short* __restrict__ H3,
                                                const float* __restrict__ cmH,
                                                unsigned char* __restrict__ H8) {
    int i = blockIdx.x * blockDim.x + threadIdx.x;
    if (i >= NN * 16) return;
    int row = i >> 4;
    int c = (i & 15) * 4;
    unsigned int pk;
    if (c < FOUT) {
        uint2 u = *(const uint2*)(H3 + (size_t)row * FOUT + c);
        float v0 = __uint_as_float(u.x << 16);
        float v1 = __uint_as_float(u.x & 0xffff0000u);
        float v2 = __uint_as_float(u.y << 16);
        float v3 = __uint_as_float(u.y & 0xffff0000u);
        float m0 = cmH[c], m1 = cmH[c + 1], m2 = cmH[c + 2], m3 = cmH[c + 3];
        float i0 = m0 > 0.f ? 127.f / m0 : 0.f;
        float i1 = m1 > 0.f ? 127.f / m1 : 0.f;
        float i2 = m2 > 0.f ? 127.f / m2 : 0.f;
        float i3 = m3 > 0.f ? 127.f / m3 : 0.f;
        int q0 = (int)rintf(v0 * i0) + 128;
        int q1 = (int)rintf(v1 * i1) + 128;
        int q2 = (int)rintf(v2 * i2) + 128;
        int q3 = (int)rintf(v3 * i3) + 128;
        pk = (unsigned int)(q0 & 0xff) | ((unsigned int)(q1 & 0xff) << 8) |
             ((unsigned int)(q2 & 0xff) << 16) | ((unsigned int)(q3 & 0xff) << 24);
    } else {
        pk = 0x80808080u;
    }
    *(unsigned int*)(H8 + (size_t)row * 64 + c) = pk;
}

// ---- final aggregation from excess-128 H8 (64B rows), integer adds ----
__global__ __launch_bounds__(256) void k_aggfb8(const unsigned char* __restrict__ tab,
                                                const float* __restrict__ cmH,
                                                const float* __restrict__ dinv,
                                                const int* __restrict__ rowptr,
                                                const int* __restrict__ cnt,
                                                const int* __restrict__ csr,
                                                const float* __restrict__ bias,
                                                float* __restrict__ out) {
    const int wid = threadIdx.x >> 6;
    const int lane = threadIdx.x & 63;
    const int wstep = (blockDim.x >> 6) * gridDim.x;
    const float cs = (lane < FOUT) ? cmH[lane] * (1.f / 127.f) : 0.f;
    for (int row = blockIdx.x * (blockDim.x >> 6) + wid; row < NN; row += wstep) {
        unsigned int acc = tab[(size_t)row * 64 + lane];
        const int rp = rowptr[row];
        const int cn = cnt[row];
        for (int e = 0; e < cn; e += 64) {
            int rem = min(cn - e, 64);
            int myidx = (lane < rem) ? csr[rp + e + lane] : 0;
            int q = 0;
            for (; q + 8 <= rem; q += 8) {
                unsigned int u[8];
#pragma unroll
                for (int j = 0; j < 8; j++) {
                    int idx = __shfl(myidx, q + j);
                    u[j] = tab[(size_t)idx * 64 + lane];
                }
#pragma unroll
                for (int j = 0; j < 8; j++) acc += u[j];
            }
            for (; q < rem; q++) {
                int idx = __shfl(myidx, q);
                acc += tab[(size_t)idx * 64 + lane];
            }
        }
        float v = cs * ((float)acc - 128.f * (float)(cn + 1));
        if (lane < FOUT) out[(size_t)row * FOUT + lane] = v * dinv[row] + bias[lane];
    }
}

__global__ void k_bnfold(const float* __restrict__ s1, const float* __restrict__ s2,
                         const float* __restrict__ g, const float* __restrict__ be,
                         float* __restrict__ scale, float* __restrict__ shift) {
    int c = threadIdx.x;
    if (c < 256) {
        float mean = s1[c] * (1.f / NN);
        float var = s2[c] * (1.f / NN) - mean * mean;
        float sc = g[c] * rsqrtf(var + EPSV);
        scale[c] = sc;
        shift[c] = be[c] - mean * sc;
    }
}

// ---- BN+ReLU bf16 -> dinv-prescaled bf16 y2 (for mgemm3) ----
__global__ void k_bnr(const unsigned short* __restrict__ x,
                      const float* __restrict__ scale, const float* __restrict__ shift,
                      const float* __restrict__ dinv, unsigned short* __restrict__ oy) {
    int i = blockIdx.x * blockDim.x + threadIdx.x;
    if (i >= NN * 128) return;
    int row = i >> 7;
    int c = (i & 127) * 2;
    unsigned int u = ((const unsigned int*)x)[i];
    float x0 = __uint_as_float(u << 16);
    float x1 = __uint_as_float(u & 0xffff0000u);
    float d = dinv[row];
    float v0 = fmaxf(x0 * scale[c + 0] + shift[c + 0], 0.f) * d;
    float v1 = fmaxf(x1 * scale[c + 1] + shift[c + 1], 0.f) * d;
    ((unsigned int*)oy)[i] = (unsigned int)f2bf(v0) | ((unsigned int)f2bf(v1) << 16);
}

extern "C" void kernel_launch(void* const* d_in, const int* in_sizes, int n_in,
                              void* d_out, int out_size, void* d_ws, size_t ws_size,
                              hipStream_t stream) {
    const int* ei = (const int*)d_in[0];
    const float* z = (const float*)d_in[1];
    const float* W1 = (const float*)d_in[2];
    const float* b1 = (const float*)d_in[3];
    const float* g1 = (const float*)d_in[4];
    const float* be1 = (const float*)d_in[5];
    const float* W2 = (const float*)d_in[6];
    const float* b2 = (const float*)d_in[7];
    const float* g2 = (const float*)d_in[8];
    const float* be2 = (const float*)d_in[9];
    const float* W3 = (const float*)d_in[10];
    const float* b3 = (const float*)d_in[11];
    float* out = (float*)d_out;

    char* w = (char*)d_ws;
    size_t o = 0;
    auto take = [&](size_t bytes) {
        char* p = w + o;
        o = (o + bytes + 255) & ~(size_t)255;
        return p;
    };
    int* cnt = (int*)take((size_t)NN * 4);
    int* rowptr = (int*)take((size_t)NN * 4);
    int* gcur = (int*)take(NBKT * 4);
    int* bbase = (int*)take(NBKT * 4);
    int* csr = (int*)take((size_t)NE * 4);
    unsigned int* staging = (unsigned int*)take((size_t)NBKT * CAPB * 4);
    float* dinv = (float*)take((size_t)NN * 4);
    float* stat = (float*)take((4 * 256 + 128 + 256 + 64) * 4);   // s1a s2a s1b s2b cmZ cmY cmH
    float* sc1 = (float*)take(256 * 4);
    float* sh1 = (float*)take(256 * 4);
    float* sc2 = (float*)take(256 * 4);
    float* sh2 = (float*)take(256 * 4);
    unsigned short* Wt1h = (unsigned short*)take(256 * 128 * 2);
    unsigned short* Wt2h = (unsigned short*)take(256 * 256 * 2);
    unsigned short* Wt3h = (unsigned short*)take(64 * 256 * 2);
    unsigned short* Wt3l = (unsigned short*)take(64 * 256 * 2);
    unsigned char* zp8 = (unsigned char*)take((size_t)NN * FIN);
    unsigned char* y1_8 = (unsigned char*)take((size_t)NN * FH);
    unsigned char* H8 = (unsigned char*)take((size_t)NN * 64);
    unsigned short* H3 = (unsigned short*)take((size_t)NN * FOUT * 2);
    unsigned short* P1 = (unsigned short*)take((size_t)NN * 256 * 2);
    unsigned short* P2 = (unsigned short*)take((size_t)NN * 512 * 2);

    unsigned short* a1 = P1;
    unsigned short* x1 = P2;
    unsigned short* a2 = P2 + (size_t)NN * 256;
    unsigned short* x2 = P1;
    unsigned short* y2 = P2;
    float* s1a = stat, *s2a = stat + 256, *s1b = stat + 512, *s2b = stat + 768;
    float* cmZ = stat + 1024;
    float* cmY = cmZ + 128;
    float* cmH = cmY + 256;

    hipMemsetAsync(gcur, 0, NBKT * 4, stream);
    hipMemsetAsync(stat, 0, (4 * 256 + 128 + 256 + 64) * 4, stream);

    // CSR build
    k_bin<<<(NE + CHNK - 1) / CHNK, 256, 0, stream>>>(ei, gcur, staging);
    k_bucketscan<<<1, 256, 0, stream>>>(gcur, bbase);
    k_build<<<NBKT, 256, 0, stream>>>(staging, gcur, bbase, cnt, dinv, rowptr, csr);

    k_wprep<<<(256 * 128 + 256 * 256 + 64 * 256 + 255) / 256, 256, 0, stream>>>(
        W1, Wt1h, W2, Wt2h, W3, Wt3h, Wt3l);

    const int GR = (NN + 63) / 64;
    const int RB = (NN + 255) / 256;   // 391

    // layer 1
    k_cmaxZ<<<RB, 256, 0, stream>>>(z, dinv, cmZ);
    k_zpb8<<<(NN * 64 + 255) / 256, 256, 0, stream>>>(z, dinv, cmZ, zp8);
    k_agg8<128, true><<<2560, 256, 0, stream>>>(zp8, cmZ, dinv, rowptr, cnt, csr, a1);
    k_gemm<128><<<dim3(2, GR), 256, 0, stream>>>(a1, Wt1h, b1, x1, s1a, s2a);
    k_bnfold<<<1, 256, 0, stream>>>(s1a, s2a, g1, be1, sc1, sh1);
    k_cmaxY<<<RB, 256, 0, stream>>>(x1, sc1, sh1, dinv, cmY);
    k_bnr8<<<(NN * 64 + 255) / 256, 256, 0, stream>>>(x1, sc1, sh1, dinv, cmY, y1_8);

    // layer 2
    k_agg8<256, false><<<2560, 256, 0, stream>>>(y1_8, cmY, dinv, rowptr, cnt, csr, a2);
    k_gemm<256><<<dim3(2, GR), 256, 0, stream>>>(a2, Wt2h, b2, x2, s1b, s2b);
    k_bnfold<<<1, 256, 0, stream>>>(s1b, s2b, g2, be2, sc2, sh2);
    k_bnr<<<(NN * 128 + 255) / 256, 256, 0, stream>>>(x2, sc2, sh2, dinv, y2);

    // layer 3
    k_mgemm3<<<NBKT, 256, 0, stream>>>(y2, Wt3h, Wt3l, H3, cmH);
    k_quantH<<<(NN * 16 + 255) / 256, 256, 0, stream>>>(H3, cmH, H8);
    k_aggfb8<<<2560, 256, 0, stream>>>(H8, cmH, dinv, rowptr, cnt, csr, b3, out);
}